// Round 1
// baseline (634.750 us; speedup 1.0000x reference)
//
#include <hip/hip_runtime.h>
#include <math.h>

// Problem constants
#define BB   256   // batch
#define TT   256   // sequence
#define CIN  384   // n_embed
#define HS   64    // head size
#define BT   (BB*TT)

#define NEG_BIG (-3.0e38f)

// ---------------------------------------------------------------------------
// Kernel 1: fused QKV projection.
// GEMM [65536 x 384] * [384 x 192] split as 3 waves per block (q/k/v).
// Block: 192 threads (3 waves). Each block computes 32 rows x 192 cols.
// x tile (32x384 fp32 = 48KB) staged in LDS; inner loop reads are
// wave-uniform-address (broadcast, conflict-free) float4 LDS reads.
// W reads are coalesced (64 consecutive floats per wave per k-step), served
// from L2 (W is only 288KB total).
// ---------------------------------------------------------------------------
__global__ __launch_bounds__(192) void qkv_kernel(
    const float* __restrict__ x,
    const float* __restrict__ Wq,
    const float* __restrict__ Wk,
    const float* __restrict__ Wv,
    float* __restrict__ q,
    float* __restrict__ k,
    float* __restrict__ v)
{
    __shared__ float xt[32 * 384];   // 48 KB

    const int tid  = threadIdx.x;
    const int row0 = blockIdx.x * 32;

    // Stage 32x384 fp32 tile: 3072 float4, 16 per thread, coalesced.
    const float4* xg  = (const float4*)(x + (size_t)row0 * 384);
    float4*       xt4 = (float4*)xt;
#pragma unroll
    for (int i = 0; i < 16; ++i)
        xt4[i * 192 + tid] = xg[i * 192 + tid];
    __syncthreads();

    const int w = tid >> 6;      // 0=q, 1=k, 2=v
    const int h = tid & 63;
    const float* W = (w == 0) ? Wq : (w == 1) ? Wk : Wv;
    float*       o = (w == 0) ? q  : (w == 1) ? k  : v;

    float acc[32];
#pragma unroll
    for (int r = 0; r < 32; ++r) acc[r] = 0.f;

    for (int kk = 0; kk < 384; kk += 4) {
        // Coalesced W loads (lane h => consecutive addresses)
        const float w0 = W[(kk + 0) * 64 + h];
        const float w1 = W[(kk + 1) * 64 + h];
        const float w2 = W[(kk + 2) * 64 + h];
        const float w3 = W[(kk + 3) * 64 + h];
#pragma unroll
        for (int r = 0; r < 32; ++r) {
            // wave-uniform address -> LDS broadcast (no bank conflict)
            float4 xv = *(const float4*)&xt[r * 384 + kk];
            acc[r] += xv.x * w0 + xv.y * w1 + xv.z * w2 + xv.w * w3;
        }
    }

#pragma unroll
    for (int r = 0; r < 32; ++r)
        o[(size_t)(row0 + r) * 64 + h] = acc[r];
}

// ---------------------------------------------------------------------------
// Kernel 2: causal attention with online softmax.
// One block per batch element b; thread t owns query row t.
// K/V staged in LDS in two 128-key tiles (64 KB total LDS).
// Wave-uniform j bound ((wave+1)*64) skips the strictly-upper tiles.
// All inner LDS reads are wave-uniform-address broadcasts.
// ---------------------------------------------------------------------------
__global__ __launch_bounds__(256, 1) void attn_kernel(
    const float* __restrict__ q,
    const float* __restrict__ k,
    const float* __restrict__ v,
    float* __restrict__ out)
{
    __shared__ float4 ks[128 * 16];  // 32 KB (128 keys x 64 fp32)
    __shared__ float4 vs[128 * 16];  // 32 KB

    const int tid = threadIdx.x;
    const int b   = blockIdx.x;
    const int t   = tid;

    // Load my query row into registers (64 fp32 = 16 float4).
    float4 qr[16];
    const float4* qg = (const float4*)(q + ((size_t)b * 256 + t) * 64);
#pragma unroll
    for (int i = 0; i < 16; ++i) qr[i] = qg[i];

    const int jend = ((tid >> 6) + 1) * 64;   // wave-uniform upper bound

    float  m = NEG_BIG;
    float  l = 0.f;
    float4 acc[16];
#pragma unroll
    for (int i = 0; i < 16; ++i) acc[i] = make_float4(0.f, 0.f, 0.f, 0.f);

    const float scale = 0.051031036307982884f;  // 384^-0.5

    for (int tile = 0; tile < 2; ++tile) {
        const int jbase = tile * 128;

        __syncthreads();  // protect previous tile's LDS contents
        {
            const float4* kg = (const float4*)(k + ((size_t)b * 256 + jbase) * 64);
            const float4* vg = (const float4*)(v + ((size_t)b * 256 + jbase) * 64);
#pragma unroll
            for (int i = 0; i < 8; ++i) {
                ks[i * 256 + tid] = kg[i * 256 + tid];
                vs[i * 256 + tid] = vg[i * 256 + tid];
            }
        }
        __syncthreads();

        if (jbase >= jend) continue;   // wave-uniform; barriers above still
                                       // execute on the next iteration for
                                       // every thread (loop is uniform).

        const int jstop = (jend - jbase < 128) ? (jend - jbase) : 128;

        for (int j0 = 0; j0 < jstop; j0 += 8) {
            // --- scores for 8 keys (8 independent FMA chains for ILP) ---
            float s[8];
#pragma unroll
            for (int i = 0; i < 8; ++i) s[i] = 0.f;
#pragma unroll
            for (int hh = 0; hh < 16; ++hh) {
                const float4 qv = qr[hh];
#pragma unroll
                for (int i = 0; i < 8; ++i) {
                    const float4 kv = ks[(j0 + i) * 16 + hh];
                    s[i] += qv.x * kv.x + qv.y * kv.y + qv.z * kv.z + qv.w * kv.w;
                }
            }

            // --- causal mask + chunk max ---
            float cmax = NEG_BIG;
#pragma unroll
            for (int i = 0; i < 8; ++i) {
                s[i] = ((jbase + j0 + i) <= t) ? s[i] * scale : NEG_BIG;
                cmax = fmaxf(cmax, s[i]);
            }

            const float mnew = fmaxf(m, cmax);
            const float r    = __expf(m - mnew);   // m=-3e38 first chunk -> 0
            l *= r;

            float p[8];
#pragma unroll
            for (int i = 0; i < 8; ++i) {
                p[i] = __expf(s[i] - mnew);        // masked -> exp(-huge) = 0
                l += p[i];
            }

            // --- rescale accumulator once per chunk, then += P*V ---
#pragma unroll
            for (int hh = 0; hh < 16; ++hh) {
                float4 a = acc[hh];
                a.x *= r; a.y *= r; a.z *= r; a.w *= r;
#pragma unroll
                for (int i = 0; i < 8; ++i) {
                    const float4 vv = vs[(j0 + i) * 16 + hh];
                    a.x += p[i] * vv.x;
                    a.y += p[i] * vv.y;
                    a.z += p[i] * vv.z;
                    a.w += p[i] * vv.w;
                }
                acc[hh] = a;
            }
            m = mnew;
        }
    }

    const float inv = 1.f / l;
    float4* og = (float4*)(out + ((size_t)b * 256 + t) * 64);
#pragma unroll
    for (int i = 0; i < 16; ++i) {
        float4 a = acc[i];
        a.x *= inv; a.y *= inv; a.z *= inv; a.w *= inv;
        og[i] = a;
    }
}

// ---------------------------------------------------------------------------
// Launch
// ---------------------------------------------------------------------------
extern "C" void kernel_launch(void* const* d_in, const int* in_sizes, int n_in,
                              void* d_out, int out_size, void* d_ws, size_t ws_size,
                              hipStream_t stream)
{
    const float* x  = (const float*)d_in[0];
    const float* Wq = (const float*)d_in[1];
    const float* Wk = (const float*)d_in[2];
    const float* Wv = (const float*)d_in[3];
    float* out = (float*)d_out;

    // Workspace: q, k, v each B*T*H fp32 (16.78 MB each, 50.3 MB total).
    float* qws = (float*)d_ws;
    float* kws = qws + (size_t)BT * HS;
    float* vws = kws + (size_t)BT * HS;

    qkv_kernel<<<BT / 32, 192, 0, stream>>>(x, Wq, Wk, Wv, qws, kws, vws);
    attn_kernel<<<BB, 256, 0, stream>>>(qws, kws, vws, out);
}

// Round 2
// 372.652 us; speedup vs baseline: 1.7033x; 1.7033x over previous
//
#include <hip/hip_runtime.h>
#include <hip/hip_bf16.h>
#include <math.h>

// Problem constants
#define BB   256   // batch
#define TT   256   // sequence
#define CIN  384   // n_embed
#define HS   64    // head size
#define BT   (BB*TT)

#define NEG_BIG (-3.0e38f)

typedef __attribute__((ext_vector_type(8))) short short8;   // 8 bf16 = 4 VGPR
typedef __attribute__((ext_vector_type(4))) float floatx4;  // MFMA C/D

__device__ inline short bf16bits(float f) {
    __hip_bfloat16 h = __float2bfloat16(f);
    union { __hip_bfloat16 h; short s; } u; u.h = h; return u.s;
}

__device__ inline short8 cvt8(const float4& f0, const float4& f1) {
    union { __hip_bfloat162 h[4]; short8 s8; } u;
    u.h[0] = __float22bfloat162_rn(make_float2(f0.x, f0.y));
    u.h[1] = __float22bfloat162_rn(make_float2(f0.z, f0.w));
    u.h[2] = __float22bfloat162_rn(make_float2(f1.x, f1.y));
    u.h[3] = __float22bfloat162_rn(make_float2(f1.z, f1.w));
    return u.s8;
}

// ---------------------------------------------------------------------------
// Kernel 0: pack Wq|Wk|Wv -> Wt[n][k] bf16, n=0..191 (q:0-63,k:64-127,v:128-191)
// 147 KB, L2-resident for the GEMM. Uncoalesced reads but tiny.
// ---------------------------------------------------------------------------
__global__ __launch_bounds__(256) void prep_wt(
    const float* __restrict__ Wq, const float* __restrict__ Wk,
    const float* __restrict__ Wv, short* __restrict__ Wt)
{
    const int idx = blockIdx.x * 256 + threadIdx.x;   // 0 .. 192*384-1
    const int n  = idx / 384;
    const int kk = idx - n * 384;
    const float* W = (n < 64) ? Wq : (n < 128) ? Wk : Wv;
    Wt[idx] = bf16bits(W[kk * 64 + (n & 63)]);
}

// ---------------------------------------------------------------------------
// Kernel 1: QKV projection as bf16 MFMA GEMM, direct-from-global (no LDS).
// C[65536 x 192] = X[65536 x 384] * Wt^T.  512 blocks x 256 thr (4 waves).
// Block tile 128(M) x 192(N); wave (wm,wn) owns 64(M) x 96(N) = 4x6 tiles
// of 16x16, K-loop 12 steps of 32 (mfma_f32_16x16x32_bf16).
// A frags: fp32 from x, converted in-register (16 rows x 128B chunks).
// B frags: bf16 16B/lane from L2-resident Wt.
// Fragment maps (guide §3): A/B [dim=lane&15][k=(lane>>4)*8+j];
// C/D col=lane&15, row=(lane>>4)*4+reg.
// ---------------------------------------------------------------------------
__global__ __launch_bounds__(256) void qkv_mfma(
    const float* __restrict__ x, const short* __restrict__ Wt,
    float* __restrict__ q, float* __restrict__ k, float* __restrict__ v)
{
    const int tid  = threadIdx.x;
    const int lane = tid & 63;
    const int wave = tid >> 6;
    const int wm   = wave >> 1;          // 0..1 : M half
    const int wn   = wave & 1;           // 0..1 : N half
    const int l15  = lane & 15;
    const int kq   = (lane >> 4) * 8;    // k offset within 32-step

    const int mbase = blockIdx.x * 128 + wm * 64;   // wave's first M row
    const int nbase = wn * 96;                      // wave's first N col

    floatx4 acc[4][6] = {};

    const float* xp[4];
    const short* wp[6];
#pragma unroll
    for (int mt = 0; mt < 4; ++mt)
        xp[mt] = x + (size_t)(mbase + mt * 16 + l15) * 384 + kq;
#pragma unroll
    for (int nt = 0; nt < 6; ++nt)
        wp[nt] = Wt + (size_t)(nbase + nt * 16 + l15) * 384 + kq;

    for (int kk = 0; kk < 384; kk += 32) {
        short8 a[4], b[6];
#pragma unroll
        for (int mt = 0; mt < 4; ++mt) {
            const float4 f0 = *(const float4*)(xp[mt] + kk);
            const float4 f1 = *(const float4*)(xp[mt] + kk + 4);
            a[mt] = cvt8(f0, f1);
        }
#pragma unroll
        for (int nt = 0; nt < 6; ++nt)
            b[nt] = *(const short8*)(wp[nt] + kk);
#pragma unroll
        for (int mt = 0; mt < 4; ++mt)
#pragma unroll
            for (int nt = 0; nt < 6; ++nt)
                acc[mt][nt] = __builtin_amdgcn_mfma_f32_16x16x32_bf16(
                    a[mt], b[nt], acc[mt][nt], 0, 0, 0);
    }

    // Epilogue: C/D col = lane&15 (n), row = (lane>>4)*4 + reg (m).
    const int crow = (lane >> 4) * 4;
#pragma unroll
    for (int nt = 0; nt < 6; ++nt) {
        const int n = nbase + nt * 16 + l15;
        float* o; int h;
        if (n < 64)       { o = q; h = n; }
        else if (n < 128) { o = k; h = n - 64; }
        else              { o = v; h = n - 128; }
#pragma unroll
        for (int mt = 0; mt < 4; ++mt) {
            const int m = mbase + mt * 16 + crow;
#pragma unroll
            for (int r = 0; r < 4; ++r)
                o[(size_t)(m + r) * 64 + h] = acc[mt][nt][r];
        }
    }
}

// ---------------------------------------------------------------------------
// Kernel 2: causal attention with online softmax (unchanged from R1).
// One block per batch element b; thread t owns query row t.
// ---------------------------------------------------------------------------
__global__ __launch_bounds__(256, 1) void attn_kernel(
    const float* __restrict__ q,
    const float* __restrict__ k,
    const float* __restrict__ v,
    float* __restrict__ out)
{
    __shared__ float4 ks[128 * 16];  // 32 KB
    __shared__ float4 vs[128 * 16];  // 32 KB

    const int tid = threadIdx.x;
    const int b   = blockIdx.x;
    const int t   = tid;

    float4 qr[16];
    const float4* qg = (const float4*)(q + ((size_t)b * 256 + t) * 64);
#pragma unroll
    for (int i = 0; i < 16; ++i) qr[i] = qg[i];

    const int jend = ((tid >> 6) + 1) * 64;   // wave-uniform upper bound

    float  m = NEG_BIG;
    float  l = 0.f;
    float4 acc[16];
#pragma unroll
    for (int i = 0; i < 16; ++i) acc[i] = make_float4(0.f, 0.f, 0.f, 0.f);

    const float scale = 0.051031036307982884f;  // 384^-0.5

    for (int tile = 0; tile < 2; ++tile) {
        const int jbase = tile * 128;

        __syncthreads();
        {
            const float4* kg = (const float4*)(k + ((size_t)b * 256 + jbase) * 64);
            const float4* vg = (const float4*)(v + ((size_t)b * 256 + jbase) * 64);
#pragma unroll
            for (int i = 0; i < 8; ++i) {
                ks[i * 256 + tid] = kg[i * 256 + tid];
                vs[i * 256 + tid] = vg[i * 256 + tid];
            }
        }
        __syncthreads();

        if (jbase >= jend) continue;

        const int jstop = (jend - jbase < 128) ? (jend - jbase) : 128;

        for (int j0 = 0; j0 < jstop; j0 += 8) {
            float s[8];
#pragma unroll
            for (int i = 0; i < 8; ++i) s[i] = 0.f;
#pragma unroll
            for (int hh = 0; hh < 16; ++hh) {
                const float4 qv = qr[hh];
#pragma unroll
                for (int i = 0; i < 8; ++i) {
                    const float4 kv = ks[(j0 + i) * 16 + hh];
                    s[i] += qv.x * kv.x + qv.y * kv.y + qv.z * kv.z + qv.w * kv.w;
                }
            }

            float cmax = NEG_BIG;
#pragma unroll
            for (int i = 0; i < 8; ++i) {
                s[i] = ((jbase + j0 + i) <= t) ? s[i] * scale : NEG_BIG;
                cmax = fmaxf(cmax, s[i]);
            }

            const float mnew = fmaxf(m, cmax);
            const float r    = __expf(m - mnew);
            l *= r;

            float p[8];
#pragma unroll
            for (int i = 0; i < 8; ++i) {
                p[i] = __expf(s[i] - mnew);
                l += p[i];
            }

#pragma unroll
            for (int hh = 0; hh < 16; ++hh) {
                float4 a = acc[hh];
                a.x *= r; a.y *= r; a.z *= r; a.w *= r;
#pragma unroll
                for (int i = 0; i < 8; ++i) {
                    const float4 vv = vs[(j0 + i) * 16 + hh];
                    a.x += p[i] * vv.x;
                    a.y += p[i] * vv.y;
                    a.z += p[i] * vv.z;
                    a.w += p[i] * vv.w;
                }
                acc[hh] = a;
            }
            m = mnew;
        }
    }

    const float inv = 1.f / l;
    float4* og = (float4*)(out + ((size_t)b * 256 + t) * 64);
#pragma unroll
    for (int i = 0; i < 16; ++i) {
        float4 a = acc[i];
        a.x *= inv; a.y *= inv; a.z *= inv; a.w *= inv;
        og[i] = a;
    }
}

// ---------------------------------------------------------------------------
// Launch
// ---------------------------------------------------------------------------
extern "C" void kernel_launch(void* const* d_in, const int* in_sizes, int n_in,
                              void* d_out, int out_size, void* d_ws, size_t ws_size,
                              hipStream_t stream)
{
    const float* x  = (const float*)d_in[0];
    const float* Wq = (const float*)d_in[1];
    const float* Wk = (const float*)d_in[2];
    const float* Wv = (const float*)d_in[3];
    float* out = (float*)d_out;

    // Workspace: Wt bf16 [192*384] (144 KB, padded to 256 KB), then q,k,v fp32.
    short* Wt  = (short*)d_ws;
    float* qws = (float*)((char*)d_ws + 256 * 1024);
    float* kws = qws + (size_t)BT * HS;
    float* vws = kws + (size_t)BT * HS;

    prep_wt<<<(192 * 384) / 256, 256, 0, stream>>>(Wq, Wk, Wv, Wt);
    qkv_mfma<<<BT / 128, 256, 0, stream>>>(x, Wt, qws, kws, vws);
    attn_kernel<<<BB, 256, 0, stream>>>(qws, kws, vws, out);
}

// Round 3
// 222.298 us; speedup vs baseline: 2.8554x; 1.6764x over previous
//
#include <hip/hip_runtime.h>
#include <hip/hip_bf16.h>
#include <math.h>

// Problem constants
#define BB   256   // batch
#define TT   256   // sequence
#define CIN  384   // n_embed
#define HS   64    // head size
#define BT   (BB*TT)

typedef __attribute__((ext_vector_type(8))) short short8;   // 8 bf16 = 4 VGPR
typedef __attribute__((ext_vector_type(4))) float floatx4;  // MFMA C/D

__device__ inline short bf16bits(float f) {
    union { __hip_bfloat16 h; short s; } u;
    u.h = __float2bfloat16(f);
    return u.s;
}

__device__ inline short8 cvt8(const float4& f0, const float4& f1) {
    union { __hip_bfloat162 h[4]; short8 s8; } u;
    u.h[0] = __float22bfloat162_rn(make_float2(f0.x, f0.y));
    u.h[1] = __float22bfloat162_rn(make_float2(f0.z, f0.w));
    u.h[2] = __float22bfloat162_rn(make_float2(f1.x, f1.y));
    u.h[3] = __float22bfloat162_rn(make_float2(f1.z, f1.w));
    return u.s8;
}

// ---------------------------------------------------------------------------
// Kernel 0: pack Wq|Wk|Wv -> Wt[n][k] bf16 (unchanged from R2)
// ---------------------------------------------------------------------------
__global__ __launch_bounds__(256) void prep_wt(
    const float* __restrict__ Wq, const float* __restrict__ Wk,
    const float* __restrict__ Wv, short* __restrict__ Wt)
{
    const int idx = blockIdx.x * 256 + threadIdx.x;
    const int n  = idx / 384;
    const int kk = idx - n * 384;
    const float* W = (n < 64) ? Wq : (n < 128) ? Wk : Wv;
    Wt[idx] = bf16bits(W[kk * 64 + (n & 63)]);
}

// ---------------------------------------------------------------------------
// Kernel 1: QKV projection as bf16 MFMA GEMM (unchanged from R2)
// ---------------------------------------------------------------------------
__global__ __launch_bounds__(256) void qkv_mfma(
    const float* __restrict__ x, const short* __restrict__ Wt,
    float* __restrict__ q, float* __restrict__ k, float* __restrict__ v)
{
    const int tid  = threadIdx.x;
    const int lane = tid & 63;
    const int wave = tid >> 6;
    const int wm   = wave >> 1;
    const int wn   = wave & 1;
    const int l15  = lane & 15;
    const int kq   = (lane >> 4) * 8;

    const int mbase = blockIdx.x * 128 + wm * 64;
    const int nbase = wn * 96;

    floatx4 acc[4][6] = {};

    const float* xp[4];
    const short* wp[6];
#pragma unroll
    for (int mt = 0; mt < 4; ++mt)
        xp[mt] = x + (size_t)(mbase + mt * 16 + l15) * 384 + kq;
#pragma unroll
    for (int nt = 0; nt < 6; ++nt)
        wp[nt] = Wt + (size_t)(nbase + nt * 16 + l15) * 384 + kq;

    for (int kk = 0; kk < 384; kk += 32) {
        short8 a[4], b[6];
#pragma unroll
        for (int mt = 0; mt < 4; ++mt) {
            const float4 f0 = *(const float4*)(xp[mt] + kk);
            const float4 f1 = *(const float4*)(xp[mt] + kk + 4);
            a[mt] = cvt8(f0, f1);
        }
#pragma unroll
        for (int nt = 0; nt < 6; ++nt)
            b[nt] = *(const short8*)(wp[nt] + kk);
#pragma unroll
        for (int mt = 0; mt < 4; ++mt)
#pragma unroll
            for (int nt = 0; nt < 6; ++nt)
                acc[mt][nt] = __builtin_amdgcn_mfma_f32_16x16x32_bf16(
                    a[mt], b[nt], acc[mt][nt], 0, 0, 0);
    }

    const int crow = (lane >> 4) * 4;
#pragma unroll
    for (int nt = 0; nt < 6; ++nt) {
        const int n = nbase + nt * 16 + l15;
        float* o; int h;
        if (n < 64)       { o = q; h = n; }
        else if (n < 128) { o = k; h = n - 64; }
        else              { o = v; h = n - 128; }
#pragma unroll
        for (int mt = 0; mt < 4; ++mt) {
            const int m = mbase + mt * 16 + crow;
#pragma unroll
            for (int r = 0; r < 4; ++r)
                o[(size_t)(m + r) * 64 + h] = acc[mt][nt][r];
        }
    }
}

// ---------------------------------------------------------------------------
// Kernel 2: MFMA flash attention.
// Grid: 1024 blocks = (b, qt) ; qt = 64-query tile. 4 waves; wave = 16 q rows.
// K staged bf16 in LDS [128x72] (2 stages of 128 keys; stage 2 skipped for
// qt<2). V staged transposed Vt[64][136] so PV B-frags are ds_read_b128.
// S = Q.K^T via mfma_16x16x32_bf16 (C: col=key, row=q). Online softmax in
// exp2 domain. P -> wave-private LDS -> A-frag for P.V (m120 pattern).
// Causal: 32-key chunks per wave, wave-divergent trip count (no barriers
// inside the chunk loop; stage loop is block-uniform).
// ---------------------------------------------------------------------------
__global__ __launch_bounds__(256) void attn_mfma(
    const float* __restrict__ q,
    const float* __restrict__ k,
    const float* __restrict__ v,
    float* __restrict__ out)
{
    __shared__ short Ks[128][72];      // 18432 B, rows 144B (16B-aligned, 2-way banks)
    __shared__ short Vt[64][136];      // 17408 B, rows 272B (16B-aligned, 2-way banks)
    __shared__ short Ps[4][16][40];    //  5120 B, rows 80B  (16B-aligned, 2-way banks)

    const int tid  = threadIdx.x;
    const int b    = blockIdx.x >> 2;
    const int qt   = blockIdx.x & 3;
    const int lane = tid & 63;
    const int w    = tid >> 6;
    const int l15  = lane & 15;
    const int quad = lane >> 4;
    const int kq   = quad * 8;          // A/B frag k-offset
    const int crow = quad * 4;          // C/D frag row base

    const int q0g  = qt * 64 + w * 16;  // wave's first q row within batch
    const int kmax = q0g + 16;          // exclusive causal key bound
    const float scl = (float)(0.051031036307982884 * 1.4426950408889634); // 384^-0.5 * log2(e)

    // Preload Q fragments (2 K-steps of 32), fp32 -> bf16 in-register.
    short8 aq[2];
    {
        const float* qp = q + (size_t)(b * 256 + q0g + l15) * 64 + kq;
        aq[0] = cvt8(*(const float4*)(qp),      *(const float4*)(qp + 4));
        aq[1] = cvt8(*(const float4*)(qp + 32), *(const float4*)(qp + 36));
    }

    float m[4], l[4];
    floatx4 O[4] = {};
#pragma unroll
    for (int r = 0; r < 4; ++r) { m[r] = -1e30f; l[r] = 0.f; }

    const int nstages = (qt >= 2) ? 2 : 1;
    for (int s = 0; s < nstages; ++s) {
        if (s) __syncthreads();
        const int sbase = s * 128;

        // --- stage K: 128 keys x 64, coalesced float4 reads ---
#pragma unroll
        for (int i = 0; i < 4; ++i) {
            const int idx = i * 256 + tid;          // 0..1023
            const int key = idx >> 3;
            const int c8  = (idx & 7) * 8;
            const float* kp = k + (size_t)(b * 256 + sbase + key) * 64 + c8;
            *(short8*)&Ks[key][c8] = cvt8(*(const float4*)kp, *(const float4*)(kp + 4));
        }
        // --- stage V transposed: coalesced dword reads, scattered b16 writes ---
#pragma unroll
        for (int i = 0; i < 32; ++i) {
            const int idx = i * 256 + tid;          // 0..8191
            const int key = idx >> 6;
            const int h   = idx & 63;
            Vt[h][key] = bf16bits(v[(size_t)(b * 256 + sbase + key) * 64 + h]);
        }
        __syncthreads();

        // --- per-wave causal chunk loop (32 keys per chunk) ---
        const int rem = kmax - sbase;
        const int nch = rem >= 128 ? 4 : ((rem + 31) >> 5);   // may be <= 0
        for (int c = 0; c < nch; ++c) {
            const int cb = c * 32;   // stage-local chunk base

            // S tiles: 2 x 16 keys, K-dim 64 = 2 MFMA steps each
            floatx4 st[2];
#pragma unroll
            for (int t = 0; t < 2; ++t) {
                const short8 b0 = *(const short8*)&Ks[cb + t * 16 + l15][kq];
                const short8 b1 = *(const short8*)&Ks[cb + t * 16 + l15][32 + kq];
                floatx4 z = {};
                z = __builtin_amdgcn_mfma_f32_16x16x32_bf16(aq[0], b0, z, 0, 0, 0);
                z = __builtin_amdgcn_mfma_f32_16x16x32_bf16(aq[1], b1, z, 0, 0, 0);
                st[t] = z;
            }

            // mask + scale (exp2 domain) + chunk row-max
            float sv[2][4], mx[4];
#pragma unroll
            for (int r = 0; r < 4; ++r) mx[r] = -3.0e38f;
#pragma unroll
            for (int t = 0; t < 2; ++t)
#pragma unroll
                for (int r = 0; r < 4; ++r) {
                    const int key  = sbase + cb + t * 16 + l15;
                    const int qrow = q0g + crow + r;
                    const float xv = st[t][r] * scl;
                    sv[t][r] = (key <= qrow) ? xv : -3.0e38f;
                    mx[r] = fmaxf(mx[r], sv[t][r]);
                }
#pragma unroll
            for (int off = 1; off < 16; off <<= 1)
#pragma unroll
                for (int r = 0; r < 4; ++r)
                    mx[r] = fmaxf(mx[r], __shfl_xor(mx[r], off, 16));

            // online-softmax update; write P (bf16) to wave-private LDS
            float al[4], rl[4];
#pragma unroll
            for (int r = 0; r < 4; ++r) {
                const float mn = fmaxf(m[r], mx[r]);
                al[r] = __builtin_amdgcn_exp2f(m[r] - mn);
                m[r]  = mn;
                const float p0 = __builtin_amdgcn_exp2f(sv[0][r] - mn);
                const float p1 = __builtin_amdgcn_exp2f(sv[1][r] - mn);
                Ps[w][crow + r][l15]      = bf16bits(p0);
                Ps[w][crow + r][16 + l15] = bf16bits(p1);
                rl[r] = p0 + p1;
            }
#pragma unroll
            for (int off = 1; off < 16; off <<= 1)
#pragma unroll
                for (int r = 0; r < 4; ++r)
                    rl[r] += __shfl_xor(rl[r], off, 16);
#pragma unroll
            for (int r = 0; r < 4; ++r) l[r] = l[r] * al[r] + rl[r];

            // wave-private LDS write->read ordering (no cross-wave sharing)
            asm volatile("s_waitcnt lgkmcnt(0)" ::: "memory");

            // P.V : A-frag = P[16q x 32key], B-frags from Vt, 4 h-tiles
            const short8 pa = *(const short8*)&Ps[w][l15][kq];
#pragma unroll
            for (int n = 0; n < 4; ++n) {
                const short8 bv = *(const short8*)&Vt[n * 16 + l15][cb + kq];
#pragma unroll
                for (int r = 0; r < 4; ++r) O[n][r] *= al[r];
                O[n] = __builtin_amdgcn_mfma_f32_16x16x32_bf16(pa, bv, O[n], 0, 0, 0);
            }
        }
    }

    // epilogue: divide by row sums, scalar dword stores (64B segments/quad)
    float inv[4];
#pragma unroll
    for (int r = 0; r < 4; ++r) inv[r] = 1.f / l[r];
#pragma unroll
    for (int n = 0; n < 4; ++n)
#pragma unroll
        for (int r = 0; r < 4; ++r)
            out[(size_t)(b * 256 + q0g + crow + r) * 64 + n * 16 + l15] = O[n][r] * inv[r];
}

// ---------------------------------------------------------------------------
// Launch
// ---------------------------------------------------------------------------
extern "C" void kernel_launch(void* const* d_in, const int* in_sizes, int n_in,
                              void* d_out, int out_size, void* d_ws, size_t ws_size,
                              hipStream_t stream)
{
    const float* x  = (const float*)d_in[0];
    const float* Wq = (const float*)d_in[1];
    const float* Wk = (const float*)d_in[2];
    const float* Wv = (const float*)d_in[3];
    float* out = (float*)d_out;

    // Workspace: Wt bf16 (256 KB pad), then q,k,v fp32.
    short* Wt  = (short*)d_ws;
    float* qws = (float*)((char*)d_ws + 256 * 1024);
    float* kws = qws + (size_t)BT * HS;
    float* vws = kws + (size_t)BT * HS;

    prep_wt<<<(192 * 384) / 256, 256, 0, stream>>>(Wq, Wk, Wv, Wt);
    qkv_mfma<<<BT / 128, 256, 0, stream>>>(x, Wt, qws, kws, vws);
    attn_mfma<<<BB * 4, 256, 0, stream>>>(qws, kws, vws, out);
}